// Round 11
// baseline (284.791 us; speedup 1.0000x reference)
//
#include <hip/hip_runtime.h>
#include <hip/hip_bf16.h>
#include <cstdint>

#define NN   50000
#define EE   800000
#define DIN_ 256
#define HD_  256     // H*DH
#define DH_  64
#define NH_  4
#define NC_  10
#define NG_  100
#define EPS_ 1e-4f
#define SLOPE_ 0.01f
#define AROW 40      // LDS row stride in ushorts (32 data + 8 pad)
#define CAP_ 48      // edge slots per node; P(deg>=48 | Poisson(16)) ~ 1e-12, guarded

typedef unsigned short ushortT;
typedef __attribute__((ext_vector_type(8))) short short8;
typedef __attribute__((ext_vector_type(4))) float f32x4;

__device__ __forceinline__ float leaky(float x) { return x >= 0.f ? x : SLOPE_ * x; }
__device__ __forceinline__ float sigm(float x)  { return 1.f / (1.f + __expf(-x)); }
__device__ __forceinline__ float b2f(ushortT u) { return __uint_as_float(((unsigned)u) << 16); }
__device__ __forceinline__ ushortT f2b(float f) {            // RNE fp32->bf16
    unsigned u = __float_as_uint(f);
    u += 0x7fffu + ((u >> 16) & 1u);
    return (ushortT)(u >> 16);
}

// ---------------- setup: zero cursor + W_feat^T bf16 + W1^T bf16 + gstart ----------------
__global__ void setup_kernel(int* cursor,
                             const float* __restrict__ W, ushortT* __restrict__ wt,
                             const float* __restrict__ W1, ushortT* __restrict__ w1t,
                             const int* __restrict__ batch, int* __restrict__ gstart) {
    int i = blockIdx.x * 256 + threadIdx.x;   // grid covers 65536
    if (i < NN) {
        cursor[i] = 0;
        int b = batch[i];
        int bp = (i == 0) ? -1 : batch[i - 1];
        for (int g = bp + 1; g <= b; g++) gstart[g] = i;
        if (i == NN - 1) {
            for (int g = b + 1; g <= NG_; g++) gstart[g] = NN;
        }
    }
    if (i < DIN_ * HD_) {
        int k = i >> 8, n = i & 255;
        wt[n * DIN_ + k] = f2b(W[i]);
    }
    if (i < 256 * 64) {
        int k = i >> 6, o = i & 63;
        w1t[o * 256 + k] = f2b(W1[i]);
    }
}

// ---------------- fused MFMA GEMM + attention (128 rows x 256 cols, x read ONCE) ----------------
// wave w owns cols [64w,64w+64) == head w; attn from fp32 accumulators via shuffles.
__global__ __launch_bounds__(256, 1) void gemm_attn(const float* __restrict__ x,
                                                    const ushortT* __restrict__ wt,
                                                    const float* __restrict__ phi,
                                                    ushortT* __restrict__ hbf,
                                                    float* __restrict__ a_s,
                                                    float* __restrict__ a_d) {
    __shared__ ushortT A_lds[128 * AROW];   // 128 rows x 32 k
    __shared__ ushortT B_lds[256 * AROW];   // 256 cols x 32 k
    const int tid  = threadIdx.x;
    const int wave = tid >> 6, lane = tid & 63;
    const int row0 = blockIdx.x * 128;
    const int q = lane >> 4, l16 = lane & 15;

    f32x4 acc[8][4];
#pragma unroll
    for (int i = 0; i < 8; i++)
#pragma unroll
        for (int j = 0; j < 4; j++) acc[i][j] = (f32x4){0.f, 0.f, 0.f, 0.f};

    const int lm  = tid >> 1;           // 0..127 (A row)
    const int lko = (tid & 1) * 16;     // 0 or 16

    for (int k0 = 0; k0 < DIN_; k0 += 32) {
        __syncthreads();
        // stage A: x[row0+lm][k0+lko..+16) fp32 -> bf16 (2 threads/row)
        {
            int gr = row0 + lm;
            float4 a0 = make_float4(0.f,0.f,0.f,0.f), a1 = a0, a2 = a0, a3 = a0;
            if (gr < NN) {
                const float4* xp = (const float4*)(x + (size_t)gr * DIN_ + k0 + lko);
                a0 = xp[0]; a1 = xp[1]; a2 = xp[2]; a3 = xp[3];
            }
            ushortT* ap = &A_lds[lm * AROW + lko];
            *(ushort4*)(ap + 0)  = make_ushort4(f2b(a0.x), f2b(a0.y), f2b(a0.z), f2b(a0.w));
            *(ushort4*)(ap + 4)  = make_ushort4(f2b(a1.x), f2b(a1.y), f2b(a1.z), f2b(a1.w));
            *(ushort4*)(ap + 8)  = make_ushort4(f2b(a2.x), f2b(a2.y), f2b(a2.z), f2b(a2.w));
            *(ushort4*)(ap + 12) = make_ushort4(f2b(a3.x), f2b(a3.y), f2b(a3.z), f2b(a3.w));
        }
        // stage B: wt[c][k0..+32), thread stages full 32-k row of col c = tid (4 uint4s)
        {
            const uint4* wp = (const uint4*)(wt + (size_t)tid * DIN_ + k0);
            uint4 b0 = wp[0], b1 = wp[1], b2 = wp[2], b3 = wp[3];
            *(uint4*)&B_lds[tid * AROW + 0]  = b0;
            *(uint4*)&B_lds[tid * AROW + 8]  = b1;
            *(uint4*)&B_lds[tid * AROW + 16] = b2;
            *(uint4*)&B_lds[tid * AROW + 24] = b3;
        }
        __syncthreads();

        short8 bf[4];
#pragma unroll
        for (int ni = 0; ni < 4; ni++)
            bf[ni] = *(const short8*)&B_lds[(wave * 64 + ni * 16 + l16) * AROW + q * 8];
#pragma unroll
        for (int mi = 0; mi < 8; mi++) {
            short8 af = *(const short8*)&A_lds[(mi * 16 + l16) * AROW + q * 8];
#pragma unroll
            for (int ni = 0; ni < 4; ni++)
                acc[mi][ni] = __builtin_amdgcn_mfma_f32_16x16x32_bf16(af, bf[ni], acc[mi][ni], 0, 0, 0);
        }
    }

    // epilogue 1: h store. D layout col=l16(+ni*16), row=q*4+reg(+mi*16)
#pragma unroll
    for (int mi = 0; mi < 8; mi++) {
        int rbase = row0 + mi * 16 + q * 4;
#pragma unroll
        for (int ni = 0; ni < 4; ni++) {
            int c = wave * 64 + ni * 16 + l16;
#pragma unroll
            for (int r = 0; r < 4; r++) {
                int gr = rbase + r;
                if (gr < NN) hbf[(size_t)gr * HD_ + c] = f2b(acc[mi][ni][r]);
            }
        }
    }

    // epilogue 2: attn for head = wave
    float phs[4], phd[4];
#pragma unroll
    for (int ni = 0; ni < 4; ni++) {
        phs[ni] = phi[wave * 128 + ni * 16 + l16];
        phd[ni] = phi[wave * 128 + 64 + ni * 16 + l16];
    }
#pragma unroll
    for (int mi = 0; mi < 8; mi++) {
#pragma unroll
        for (int r = 0; r < 4; r++) {
            float ps = acc[mi][0][r] * phs[0] + acc[mi][1][r] * phs[1]
                     + acc[mi][2][r] * phs[2] + acc[mi][3][r] * phs[3];
            float pd = acc[mi][0][r] * phd[0] + acc[mi][1][r] * phd[1]
                     + acc[mi][2][r] * phd[2] + acc[mi][3][r] * phd[3];
#pragma unroll
            for (int o = 1; o < 16; o <<= 1) {
                ps += __shfl_xor(ps, o);
                pd += __shfl_xor(pd, o);
            }
            if (l16 == 0) {
                int gr = row0 + mi * 16 + q * 4 + r;
                if (gr < NN) {
                    a_s[gr * 4 + wave] = ps;
                    a_d[gr * 4 + wave] = pd;
                }
            }
        }
    }
}

// ---------------- fill: dst-only direct-slot binning (4B record, no weight math) ----------------
__global__ void fill_edges(const int* __restrict__ src, const int* __restrict__ dstA,
                           int* __restrict__ cursor, int* __restrict__ edge_dst) {
    int e = blockIdx.x * 256 + threadIdx.x;
    if (e >= EE) return;
    int s = src[e];
    int slot = atomicAdd(&cursor[s], 1);
    if (slot >= CAP_) return;   // statistically impossible; guarded
    edge_dst[s * CAP_ + slot] = dstA[e];
}

// ---------------- aggregation: one wave per node; weights computed inline ----------------
__global__ __launch_bounds__(256) void agg_kernel(const ushortT* __restrict__ hbf,
                                                  const int* __restrict__ cursor,
                                                  const int* __restrict__ edge_dst,
                                                  const float* __restrict__ a_s,
                                                  const float* __restrict__ a_d,
                                                  ushortT* __restrict__ aggB) {
    int wv = threadIdx.x >> 6, lane = threadIdx.x & 63;
    int n = blockIdx.x * 4 + wv;   // grid 12500*4 == 50000
    int hsel = lane >> 4;
    int cnt = cursor[n];
    if (cnt > CAP_) cnt = CAP_;
    int e0 = n * CAP_, e1 = e0 + cnt;
    float as_h = a_s[n * 4 + hsel];
    float4 acc = make_float4(0.f, 0.f, 0.f, 0.f);
    const ushortT* hbase = hbf + (size_t)lane * 4;

    int i = e0;
    while (i + 8 <= e1) {
        int dd[8]; float ad[8]; ushort4 hh[8];
#pragma unroll
        for (int j = 0; j < 8; j++) dd[j] = edge_dst[i + j];
#pragma unroll
        for (int j = 0; j < 8; j++) {
            ad[j] = a_d[dd[j] * 4 + hsel];
            hh[j] = *(const ushort4*)(hbase + (size_t)dd[j] * HD_);
        }
#pragma unroll
        for (int j = 0; j < 8; j++) {
            float w = sigm(leaky(as_h + ad[j]));
            acc.x += b2f(hh[j].x) * w;
            acc.y += b2f(hh[j].y) * w;
            acc.z += b2f(hh[j].z) * w;
            acc.w += b2f(hh[j].w) * w;
        }
        i += 8;
    }
    while (i + 4 <= e1) {
        int dd[4]; float ad[4]; ushort4 hh[4];
#pragma unroll
        for (int j = 0; j < 4; j++) dd[j] = edge_dst[i + j];
#pragma unroll
        for (int j = 0; j < 4; j++) {
            ad[j] = a_d[dd[j] * 4 + hsel];
            hh[j] = *(const ushort4*)(hbase + (size_t)dd[j] * HD_);
        }
#pragma unroll
        for (int j = 0; j < 4; j++) {
            float w = sigm(leaky(as_h + ad[j]));
            acc.x += b2f(hh[j].x) * w;
            acc.y += b2f(hh[j].y) * w;
            acc.z += b2f(hh[j].z) * w;
            acc.w += b2f(hh[j].w) * w;
        }
        i += 4;
    }
    for (; i < e1; i++) {
        int d = edge_dst[i];
        float w = sigm(leaky(as_h + a_d[d * 4 + hsel]));
        ushort4 hv = *(const ushort4*)(hbase + (size_t)d * HD_);
        acc.x += b2f(hv.x) * w; acc.y += b2f(hv.y) * w;
        acc.z += b2f(hv.z) * w; acc.w += b2f(hv.w) * w;
    }
    ushort4 o4 = make_ushort4(f2b(acc.x), f2b(acc.y), f2b(acc.z), f2b(acc.w));
    *(ushort4*)(aggB + (size_t)n * HD_ + lane * 4) = o4;
}

// ---------------- MLP: MFMA stage-1, softmax, preds ----------------
__global__ __launch_bounds__(256) void mlp_kernel(const ushortT* __restrict__ aggB,
                                                  const ushortT* __restrict__ w1t,
                                                  const float* __restrict__ b1,
                                                  const float* __restrict__ W2,
                                                  const float* __restrict__ b2,
                                                  float* __restrict__ out) {
    __shared__ float z1t[64][65];   // [hidden][node]
    const int tid = threadIdx.x;
    const int wave = tid >> 6, lane = tid & 63;
    const int q = lane >> 4, l16 = lane & 15;
    const int n0 = blockIdx.x * 64;
    const int nodeRow = n0 + wave * 16 + l16;

    f32x4 acc[4];
#pragma unroll
    for (int ni = 0; ni < 4; ni++) acc[ni] = (f32x4){0.f, 0.f, 0.f, 0.f};

    const ushortT* arow = aggB + (size_t)nodeRow * HD_ + q * 8;
#pragma unroll
    for (int k0 = 0; k0 < 256; k0 += 32) {
        short8 af = *(const short8*)(arow + k0);
#pragma unroll
        for (int ni = 0; ni < 4; ni++) {
            short8 bf = *(const short8*)(w1t + (size_t)(ni * 16 + l16) * 256 + k0 + q * 8);
            acc[ni] = __builtin_amdgcn_mfma_f32_16x16x32_bf16(af, bf, acc[ni], 0, 0, 0);
        }
    }
#pragma unroll
    for (int ni = 0; ni < 4; ni++) {
        int o = ni * 16 + l16;
        float bb = b1[o];
#pragma unroll
        for (int r = 0; r < 4; r++)
            z1t[o][wave * 16 + q * 4 + r] = leaky(acc[ni][r] + bb);
    }
    __syncthreads();

    if (tid < 64) {
        int n = n0 + tid;
        if (n < NN) {
            float zc[NC_];
#pragma unroll
            for (int c = 0; c < NC_; c++) zc[c] = b2[c];
            for (int k = 0; k < 64; k++) {
                float zv = z1t[k][tid];
#pragma unroll
                for (int c = 0; c < NC_; c++) zc[c] += zv * W2[k * NC_ + c];
            }
            float m = zc[0];
#pragma unroll
            for (int c = 1; c < NC_; c++) m = fmaxf(m, zc[c]);
            float ssum = 0.f;
#pragma unroll
            for (int c = 0; c < NC_; c++) { zc[c] = __expf(zc[c] - m) + EPS_; ssum += zc[c]; }
            float inv = 1.f / ssum;
#pragma unroll
            for (int c = 0; c < NC_; c++) out[1000 + (size_t)n * NC_ + c] = zc[c] * inv;
        }
    }
}

// ---------------- group mean + log: one block per group ----------------
__global__ __launch_bounds__(256) void group_mean(const float* __restrict__ preds,
                                                  const int* __restrict__ gstart,
                                                  float* __restrict__ out) {
    __shared__ float red[16][16];
    int g = blockIdx.x;
    int t = threadIdx.x;
    int c = t & 15, chunk = t >> 4;
    int gs = gstart[g], ge = gstart[g + 1];
    float s = 0.f;
    if (c < NC_) {
        for (int n = gs + chunk; n < ge; n += 16) s += preds[(size_t)n * NC_ + c];
    }
    red[chunk][c] = s;
    __syncthreads();
    if (t < NC_) {
        float tot = 0.f;
#pragma unroll
        for (int j = 0; j < 16; j++) tot += red[j][t];
        out[g * NC_ + t] = __logf(tot / (float)(ge - gs));
    }
}

extern "C" void kernel_launch(void* const* d_in, const int* in_sizes, int n_in,
                              void* d_out, int out_size, void* d_ws, size_t ws_size,
                              hipStream_t stream) {
    const float* x      = (const float*)d_in[0];
    const int*   midx   = (const int*)d_in[1];
    const int*   batch  = (const int*)d_in[2];
    const float* W_feat = (const float*)d_in[3];
    const float* phi    = (const float*)d_in[4];
    const float* W1     = (const float*)d_in[5];
    const float* b1     = (const float*)d_in[6];
    const float* W2     = (const float*)d_in[7];
    const float* b2     = (const float*)d_in[8];
    const int* src = midx;
    const int* dst = midx + EE;
    float* out = (float*)d_out;

    char* p = (char*)d_ws;
    auto alloc = [&](size_t bytes) { void* r = (void*)p; p += (bytes + 255) & ~(size_t)255; return r; };
    ushortT* hbf      = (ushortT*)alloc((size_t)NN * HD_ * 2);
    ushortT* aggB     = (ushortT*)alloc((size_t)NN * HD_ * 2);
    int*     edge_dst = (int*)alloc((size_t)NN * CAP_ * 4);   // 9.6 MB
    ushortT* wt       = (ushortT*)alloc((size_t)DIN_ * HD_ * 2);
    ushortT* w1t      = (ushortT*)alloc((size_t)64 * 256 * 2);
    float*   a_s      = (float*)alloc((size_t)NN * 4 * 4);
    float*   a_d      = (float*)alloc((size_t)NN * 4 * 4);
    int*     cursor   = (int*)alloc((size_t)NN * 4);
    int*     gstart   = (int*)alloc((size_t)(NG_ + 1) * 4);

    setup_kernel<<<256, 256, 0, stream>>>(cursor, W_feat, wt, W1, w1t, batch, gstart);
    gemm_attn<<<(NN + 127) / 128, 256, 0, stream>>>(x, wt, phi, hbf, a_s, a_d);
    fill_edges<<<(EE + 255) / 256, 256, 0, stream>>>(src, dst, cursor, edge_dst);
    agg_kernel<<<NN / 4, 256, 0, stream>>>(hbf, cursor, edge_dst, a_s, a_d, aggB);
    mlp_kernel<<<(NN + 63) / 64, 256, 0, stream>>>(aggB, w1t, b1, W2, b2, out);
    group_mean<<<NG_, 256, 0, stream>>>(out + 1000, gstart, out);
}

// Round 12
// 265.727 us; speedup vs baseline: 1.0717x; 1.0717x over previous
//
#include <hip/hip_runtime.h>
#include <hip/hip_bf16.h>
#include <cstdint>

#define NN   50000
#define EE   800000
#define DIN_ 256
#define HD_  256     // H*DH
#define DH_  64
#define NH_  4
#define NC_  10
#define NG_  100
#define EPS_ 1e-4f
#define SLOPE_ 0.01f
#define AROW 40      // LDS row stride in ushorts (32 data + 8 pad)
#define CAP_ 48      // edge slots per node; P(deg>=48 | Poisson(16)) ~ 1e-12, guarded

typedef unsigned short ushortT;
typedef __attribute__((ext_vector_type(8))) short short8;
typedef __attribute__((ext_vector_type(4))) float f32x4;

__device__ __forceinline__ float leaky(float x) { return x >= 0.f ? x : SLOPE_ * x; }
__device__ __forceinline__ float sigm(float x)  { return 1.f / (1.f + __expf(-x)); }
__device__ __forceinline__ float b2f(ushortT u) { return __uint_as_float(((unsigned)u) << 16); }
__device__ __forceinline__ ushortT f2b(float f) {            // RNE fp32->bf16
    unsigned u = __float_as_uint(f);
    u += 0x7fffu + ((u >> 16) & 1u);
    return (ushortT)(u >> 16);
}

// ---------------- setup: zero cursor + W_feat^T bf16 + W1^T bf16 + gstart ----------------
__global__ void setup_kernel(int* cursor,
                             const float* __restrict__ W, ushortT* __restrict__ wt,
                             const float* __restrict__ W1, ushortT* __restrict__ w1t,
                             const int* __restrict__ batch, int* __restrict__ gstart) {
    int i = blockIdx.x * 256 + threadIdx.x;   // grid covers 65536
    if (i < NN) {
        cursor[i] = 0;
        int b = batch[i];
        int bp = (i == 0) ? -1 : batch[i - 1];
        for (int g = bp + 1; g <= b; g++) gstart[g] = i;
        if (i == NN - 1) {
            for (int g = b + 1; g <= NG_; g++) gstart[g] = NN;
        }
    }
    if (i < DIN_ * HD_) {
        int k = i >> 8, n = i & 255;
        wt[n * DIN_ + k] = f2b(W[i]);
    }
    if (i < 256 * 64) {
        int k = i >> 6, o = i & 63;
        w1t[o * 256 + k] = f2b(W1[i]);
    }
}

// ---------------- fused MFMA GEMM + attention scores (128x128 tile, 782 blocks) ----------------
__global__ __launch_bounds__(256) void gemm_attn(const float* __restrict__ x,
                                                 const ushortT* __restrict__ wt,
                                                 const float* __restrict__ phi,
                                                 ushortT* __restrict__ hbf,
                                                 float* __restrict__ a_s,
                                                 float* __restrict__ a_d) {
    __shared__ ushortT A_lds[128 * AROW];
    __shared__ ushortT B_lds[128 * AROW];
    const int tid  = threadIdx.x;
    const int wave = tid >> 6, lane = tid & 63;
    const int wm = wave >> 1, wn = wave & 1;
    const int row0 = blockIdx.x * 128;
    const int col0 = blockIdx.y * 128;
    const int q = lane >> 4, l16 = lane & 15;

    f32x4 acc[4][4];
#pragma unroll
    for (int i = 0; i < 4; i++)
#pragma unroll
        for (int j = 0; j < 4; j++) acc[i][j] = (f32x4){0.f, 0.f, 0.f, 0.f};

    const int lm  = tid >> 1;
    const int lko = (tid & 1) * 16;

    for (int k0 = 0; k0 < DIN_; k0 += 32) {
        __syncthreads();
        {
            int gr = row0 + lm;
            float4 a0 = make_float4(0.f,0.f,0.f,0.f), a1 = a0, a2 = a0, a3 = a0;
            if (gr < NN) {
                const float4* xp = (const float4*)(x + (size_t)gr * DIN_ + k0 + lko);
                a0 = xp[0]; a1 = xp[1]; a2 = xp[2]; a3 = xp[3];
            }
            ushortT* ap = &A_lds[lm * AROW + lko];
            *(ushort4*)(ap + 0)  = make_ushort4(f2b(a0.x), f2b(a0.y), f2b(a0.z), f2b(a0.w));
            *(ushort4*)(ap + 4)  = make_ushort4(f2b(a1.x), f2b(a1.y), f2b(a1.z), f2b(a1.w));
            *(ushort4*)(ap + 8)  = make_ushort4(f2b(a2.x), f2b(a2.y), f2b(a2.z), f2b(a2.w));
            *(ushort4*)(ap + 12) = make_ushort4(f2b(a3.x), f2b(a3.y), f2b(a3.z), f2b(a3.w));
        }
        {
            const uint4* wp = (const uint4*)(wt + (size_t)(col0 + lm) * DIN_ + k0 + lko);
            uint4 b0 = wp[0], b1 = wp[1];
            *(uint4*)&B_lds[lm * AROW + lko + 0] = b0;
            *(uint4*)&B_lds[lm * AROW + lko + 8] = b1;
        }
        __syncthreads();

        short8 af[4], bf[4];
#pragma unroll
        for (int mi = 0; mi < 4; mi++)
            af[mi] = *(const short8*)&A_lds[(wm * 64 + mi * 16 + l16) * AROW + q * 8];
#pragma unroll
        for (int ni = 0; ni < 4; ni++)
            bf[ni] = *(const short8*)&B_lds[(wn * 64 + ni * 16 + l16) * AROW + q * 8];
#pragma unroll
        for (int mi = 0; mi < 4; mi++)
#pragma unroll
            for (int ni = 0; ni < 4; ni++)
                acc[mi][ni] = __builtin_amdgcn_mfma_f32_16x16x32_bf16(af[mi], bf[ni], acc[mi][ni], 0, 0, 0);
    }

#pragma unroll
    for (int mi = 0; mi < 4; mi++) {
        int rbase = row0 + wm * 64 + mi * 16 + q * 4;
#pragma unroll
        for (int ni = 0; ni < 4; ni++) {
            int c = col0 + wn * 64 + ni * 16 + l16;
#pragma unroll
            for (int r = 0; r < 4; r++) {
                int gr = rbase + r;
                if (gr < NN) hbf[(size_t)gr * HD_ + c] = f2b(acc[mi][ni][r]);
            }
        }
    }

    int head = blockIdx.y * 2 + wn;
    float phs[4], phd[4];
#pragma unroll
    for (int ni = 0; ni < 4; ni++) {
        phs[ni] = phi[head * 128 + ni * 16 + l16];
        phd[ni] = phi[head * 128 + 64 + ni * 16 + l16];
    }
#pragma unroll
    for (int mi = 0; mi < 4; mi++) {
#pragma unroll
        for (int r = 0; r < 4; r++) {
            float ps = acc[mi][0][r] * phs[0] + acc[mi][1][r] * phs[1]
                     + acc[mi][2][r] * phs[2] + acc[mi][3][r] * phs[3];
            float pd = acc[mi][0][r] * phd[0] + acc[mi][1][r] * phd[1]
                     + acc[mi][2][r] * phd[2] + acc[mi][3][r] * phd[3];
#pragma unroll
            for (int o = 1; o < 16; o <<= 1) {
                ps += __shfl_xor(ps, o);
                pd += __shfl_xor(pd, o);
            }
            if (l16 == 0) {
                int gr = row0 + wm * 64 + mi * 16 + q * 4 + r;
                if (gr < NN) {
                    a_s[gr * 4 + head] = ps;
                    a_d[gr * 4 + head] = pd;
                }
            }
        }
    }
}

// ---------------- fill: direct-slot binning, 16B record {dst, w01, w23, 0} ----------------
__global__ void fill_edges(const int* __restrict__ src, const int* __restrict__ dstA,
                           int* __restrict__ cursor,
                           const float* __restrict__ a_s, const float* __restrict__ a_d,
                           uint4* __restrict__ edges) {
    int e = blockIdx.x * 256 + threadIdx.x;
    if (e >= EE) return;
    int s = src[e], d = dstA[e];
    int slot = atomicAdd(&cursor[s], 1);
    if (slot >= CAP_) return;   // statistically impossible; guarded
    float4 as4 = *(const float4*)(a_s + (size_t)s * 4);
    float4 ad4 = *(const float4*)(a_d + (size_t)d * 4);
    unsigned w01 = (unsigned)f2b(sigm(leaky(as4.x + ad4.x)))
                 | ((unsigned)f2b(sigm(leaky(as4.y + ad4.y))) << 16);
    unsigned w23 = (unsigned)f2b(sigm(leaky(as4.z + ad4.z)))
                 | ((unsigned)f2b(sigm(leaky(as4.w + ad4.w))) << 16);
    edges[(size_t)s * CAP_ + slot] = make_uint4((unsigned)d, w01, w23, 0u);
}

// ---------------- aggregation: one wave per node (12500 blocks), precomputed weights ----------------
__global__ __launch_bounds__(256) void agg_kernel(const ushortT* __restrict__ hbf,
                                                  const int* __restrict__ cursor,
                                                  const uint4* __restrict__ edges,
                                                  ushortT* __restrict__ aggB) {
    int wv = threadIdx.x >> 6, lane = threadIdx.x & 63;
    int n = blockIdx.x * 4 + wv;   // grid 12500*4 == 50000
    int hsel = lane >> 4;
    int wsh = (hsel & 1) * 16;
    int cnt = cursor[n];
    if (cnt > CAP_) cnt = CAP_;
    int e0 = n * CAP_, e1 = e0 + cnt;
    float4 acc = make_float4(0.f, 0.f, 0.f, 0.f);
    const ushortT* hbase = hbf + (size_t)lane * 4;

    int i = e0;
    while (i + 8 <= e1) {
        uint4 ee[8]; ushort4 hh[8]; float ww[8];
#pragma unroll
        for (int j = 0; j < 8; j++) ee[j] = edges[i + j];
#pragma unroll
        for (int j = 0; j < 8; j++) {
            unsigned pair = (hsel & 2) ? ee[j].z : ee[j].y;
            ww[j] = b2f((ushortT)((pair >> wsh) & 0xffffu));
            hh[j] = *(const ushort4*)(hbase + (size_t)ee[j].x * HD_);
        }
#pragma unroll
        for (int j = 0; j < 8; j++) {
            acc.x += b2f(hh[j].x) * ww[j];
            acc.y += b2f(hh[j].y) * ww[j];
            acc.z += b2f(hh[j].z) * ww[j];
            acc.w += b2f(hh[j].w) * ww[j];
        }
        i += 8;
    }
    while (i + 4 <= e1) {
        uint4 ee[4]; ushort4 hh[4]; float ww[4];
#pragma unroll
        for (int j = 0; j < 4; j++) ee[j] = edges[i + j];
#pragma unroll
        for (int j = 0; j < 4; j++) {
            unsigned pair = (hsel & 2) ? ee[j].z : ee[j].y;
            ww[j] = b2f((ushortT)((pair >> wsh) & 0xffffu));
            hh[j] = *(const ushort4*)(hbase + (size_t)ee[j].x * HD_);
        }
#pragma unroll
        for (int j = 0; j < 4; j++) {
            acc.x += b2f(hh[j].x) * ww[j];
            acc.y += b2f(hh[j].y) * ww[j];
            acc.z += b2f(hh[j].z) * ww[j];
            acc.w += b2f(hh[j].w) * ww[j];
        }
        i += 4;
    }
    for (; i < e1; i++) {
        uint4 e = edges[i];
        unsigned pair = (hsel & 2) ? e.z : e.y;
        float s = b2f((ushortT)((pair >> wsh) & 0xffffu));
        ushort4 hv = *(const ushort4*)(hbase + (size_t)e.x * HD_);
        acc.x += b2f(hv.x) * s; acc.y += b2f(hv.y) * s;
        acc.z += b2f(hv.z) * s; acc.w += b2f(hv.w) * s;
    }
    ushort4 o4 = make_ushort4(f2b(acc.x), f2b(acc.y), f2b(acc.z), f2b(acc.w));
    *(ushort4*)(aggB + (size_t)n * HD_ + lane * 4) = o4;
}

// ---------------- MLP: MFMA stage-1, softmax, preds ----------------
__global__ __launch_bounds__(256) void mlp_kernel(const ushortT* __restrict__ aggB,
                                                  const ushortT* __restrict__ w1t,
                                                  const float* __restrict__ b1,
                                                  const float* __restrict__ W2,
                                                  const float* __restrict__ b2,
                                                  float* __restrict__ out) {
    __shared__ float z1t[64][65];   // [hidden][node]
    const int tid = threadIdx.x;
    const int wave = tid >> 6, lane = tid & 63;
    const int q = lane >> 4, l16 = lane & 15;
    const int n0 = blockIdx.x * 64;
    const int nodeRow = n0 + wave * 16 + l16;

    f32x4 acc[4];
#pragma unroll
    for (int ni = 0; ni < 4; ni++) acc[ni] = (f32x4){0.f, 0.f, 0.f, 0.f};

    const ushortT* arow = aggB + (size_t)nodeRow * HD_ + q * 8;
#pragma unroll
    for (int k0 = 0; k0 < 256; k0 += 32) {
        short8 af = *(const short8*)(arow + k0);
#pragma unroll
        for (int ni = 0; ni < 4; ni++) {
            short8 bf = *(const short8*)(w1t + (size_t)(ni * 16 + l16) * 256 + k0 + q * 8);
            acc[ni] = __builtin_amdgcn_mfma_f32_16x16x32_bf16(af, bf, acc[ni], 0, 0, 0);
        }
    }
#pragma unroll
    for (int ni = 0; ni < 4; ni++) {
        int o = ni * 16 + l16;
        float bb = b1[o];
#pragma unroll
        for (int r = 0; r < 4; r++)
            z1t[o][wave * 16 + q * 4 + r] = leaky(acc[ni][r] + bb);
    }
    __syncthreads();

    if (tid < 64) {
        int n = n0 + tid;
        if (n < NN) {
            float zc[NC_];
#pragma unroll
            for (int c = 0; c < NC_; c++) zc[c] = b2[c];
            for (int k = 0; k < 64; k++) {
                float zv = z1t[k][tid];
#pragma unroll
                for (int c = 0; c < NC_; c++) zc[c] += zv * W2[k * NC_ + c];
            }
            float m = zc[0];
#pragma unroll
            for (int c = 1; c < NC_; c++) m = fmaxf(m, zc[c]);
            float ssum = 0.f;
#pragma unroll
            for (int c = 0; c < NC_; c++) { zc[c] = __expf(zc[c] - m) + EPS_; ssum += zc[c]; }
            float inv = 1.f / ssum;
#pragma unroll
            for (int c = 0; c < NC_; c++) out[1000 + (size_t)n * NC_ + c] = zc[c] * inv;
        }
    }
}

// ---------------- group mean + log: one block per group ----------------
__global__ __launch_bounds__(256) void group_mean(const float* __restrict__ preds,
                                                  const int* __restrict__ gstart,
                                                  float* __restrict__ out) {
    __shared__ float red[16][16];
    int g = blockIdx.x;
    int t = threadIdx.x;
    int c = t & 15, chunk = t >> 4;
    int gs = gstart[g], ge = gstart[g + 1];
    float s = 0.f;
    if (c < NC_) {
        for (int n = gs + chunk; n < ge; n += 16) s += preds[(size_t)n * NC_ + c];
    }
    red[chunk][c] = s;
    __syncthreads();
    if (t < NC_) {
        float tot = 0.f;
#pragma unroll
        for (int j = 0; j < 16; j++) tot += red[j][t];
        out[g * NC_ + t] = __logf(tot / (float)(ge - gs));
    }
}

extern "C" void kernel_launch(void* const* d_in, const int* in_sizes, int n_in,
                              void* d_out, int out_size, void* d_ws, size_t ws_size,
                              hipStream_t stream) {
    const float* x      = (const float*)d_in[0];
    const int*   midx   = (const int*)d_in[1];
    const int*   batch  = (const int*)d_in[2];
    const float* W_feat = (const float*)d_in[3];
    const float* phi    = (const float*)d_in[4];
    const float* W1     = (const float*)d_in[5];
    const float* b1     = (const float*)d_in[6];
    const float* W2     = (const float*)d_in[7];
    const float* b2     = (const float*)d_in[8];
    const int* src = midx;
    const int* dst = midx + EE;
    float* out = (float*)d_out;

    char* p = (char*)d_ws;
    auto alloc = [&](size_t bytes) { void* r = (void*)p; p += (bytes + 255) & ~(size_t)255; return r; };
    ushortT* hbf      = (ushortT*)alloc((size_t)NN * HD_ * 2);
    ushortT* aggB     = (ushortT*)alloc((size_t)NN * HD_ * 2);
    uint4*   edges    = (uint4*)alloc((size_t)NN * CAP_ * 16);   // 38.4 MB
    ushortT* wt       = (ushortT*)alloc((size_t)DIN_ * HD_ * 2);
    ushortT* w1t      = (ushortT*)alloc((size_t)64 * 256 * 2);
    float*   a_s      = (float*)alloc((size_t)NN * 4 * 4);
    float*   a_d      = (float*)alloc((size_t)NN * 4 * 4);
    int*     cursor   = (int*)alloc((size_t)NN * 4);
    int*     gstart   = (int*)alloc((size_t)(NG_ + 1) * 4);

    setup_kernel<<<256, 256, 0, stream>>>(cursor, W_feat, wt, W1, w1t, batch, gstart);
    gemm_attn<<<dim3((NN + 127) / 128, 2), 256, 0, stream>>>(x, wt, phi, hbf, a_s, a_d);
    fill_edges<<<(EE + 255) / 256, 256, 0, stream>>>(src, dst, cursor, a_s, a_d, edges);
    agg_kernel<<<NN / 4, 256, 0, stream>>>(hbf, cursor, edges, aggB);
    mlp_kernel<<<(NN + 63) / 64, 256, 0, stream>>>(aggB, w1t, b1, W2, b2, out);
    group_mean<<<NG_, 256, 0, stream>>>(out + 1000, gstart, out);
}

// Round 13
// 256.087 us; speedup vs baseline: 1.1121x; 1.0376x over previous
//
#include <hip/hip_runtime.h>
#include <hip/hip_bf16.h>
#include <cstdint>

#define NN   50000
#define EE   800000
#define DIN_ 256
#define HD_  256     // H*DH
#define DH_  64
#define NH_  4
#define NC_  10
#define NG_  100
#define EPS_ 1e-4f
#define SLOPE_ 0.01f
#define AROW 40      // gemm LDS row stride in ushorts (32 data + 8 pad)
#define CAP_ 48      // edge slots per node; P(deg>=48 | Poisson(16)) ~ 1e-12, guarded
#define FROW 264     // fused-kernel LDS agg row stride in ushorts (256 + 8 pad, 16B-aligned)

typedef unsigned short ushortT;
typedef __attribute__((ext_vector_type(8))) short short8;
typedef __attribute__((ext_vector_type(4))) float f32x4;

__device__ __forceinline__ float leaky(float x) { return x >= 0.f ? x : SLOPE_ * x; }
__device__ __forceinline__ float sigm(float x)  { return 1.f / (1.f + __expf(-x)); }
__device__ __forceinline__ float b2f(ushortT u) { return __uint_as_float(((unsigned)u) << 16); }
__device__ __forceinline__ ushortT f2b(float f) {            // RNE fp32->bf16
    unsigned u = __float_as_uint(f);
    u += 0x7fffu + ((u >> 16) & 1u);
    return (ushortT)(u >> 16);
}

// ---------------- setup: zero cursor + W_feat^T bf16 + W1^T bf16 + gstart ----------------
__global__ void setup_kernel(int* cursor,
                             const float* __restrict__ W, ushortT* __restrict__ wt,
                             const float* __restrict__ W1, ushortT* __restrict__ w1t,
                             const int* __restrict__ batch, int* __restrict__ gstart) {
    int i = blockIdx.x * 256 + threadIdx.x;   // grid covers 65536
    if (i < NN) {
        cursor[i] = 0;
        int b = batch[i];
        int bp = (i == 0) ? -1 : batch[i - 1];
        for (int g = bp + 1; g <= b; g++) gstart[g] = i;
        if (i == NN - 1) {
            for (int g = b + 1; g <= NG_; g++) gstart[g] = NN;
        }
    }
    if (i < DIN_ * HD_) {
        int k = i >> 8, n = i & 255;
        wt[n * DIN_ + k] = f2b(W[i]);
    }
    if (i < 256 * 64) {
        int k = i >> 6, o = i & 63;
        w1t[o * 256 + k] = f2b(W1[i]);
    }
}

// ---------------- fused MFMA GEMM + attention scores (128x128 tile, 782 blocks) ----------------
__global__ __launch_bounds__(256) void gemm_attn(const float* __restrict__ x,
                                                 const ushortT* __restrict__ wt,
                                                 const float* __restrict__ phi,
                                                 ushortT* __restrict__ hbf,
                                                 float* __restrict__ a_s,
                                                 float* __restrict__ a_d) {
    __shared__ ushortT A_lds[128 * AROW];
    __shared__ ushortT B_lds[128 * AROW];
    const int tid  = threadIdx.x;
    const int wave = tid >> 6, lane = tid & 63;
    const int wm = wave >> 1, wn = wave & 1;
    const int row0 = blockIdx.x * 128;
    const int col0 = blockIdx.y * 128;
    const int q = lane >> 4, l16 = lane & 15;

    f32x4 acc[4][4];
#pragma unroll
    for (int i = 0; i < 4; i++)
#pragma unroll
        for (int j = 0; j < 4; j++) acc[i][j] = (f32x4){0.f, 0.f, 0.f, 0.f};

    const int lm  = tid >> 1;
    const int lko = (tid & 1) * 16;

    for (int k0 = 0; k0 < DIN_; k0 += 32) {
        __syncthreads();
        {
            int gr = row0 + lm;
            float4 a0 = make_float4(0.f,0.f,0.f,0.f), a1 = a0, a2 = a0, a3 = a0;
            if (gr < NN) {
                const float4* xp = (const float4*)(x + (size_t)gr * DIN_ + k0 + lko);
                a0 = xp[0]; a1 = xp[1]; a2 = xp[2]; a3 = xp[3];
            }
            ushortT* ap = &A_lds[lm * AROW + lko];
            *(ushort4*)(ap + 0)  = make_ushort4(f2b(a0.x), f2b(a0.y), f2b(a0.z), f2b(a0.w));
            *(ushort4*)(ap + 4)  = make_ushort4(f2b(a1.x), f2b(a1.y), f2b(a1.z), f2b(a1.w));
            *(ushort4*)(ap + 8)  = make_ushort4(f2b(a2.x), f2b(a2.y), f2b(a2.z), f2b(a2.w));
            *(ushort4*)(ap + 12) = make_ushort4(f2b(a3.x), f2b(a3.y), f2b(a3.z), f2b(a3.w));
        }
        {
            const uint4* wp = (const uint4*)(wt + (size_t)(col0 + lm) * DIN_ + k0 + lko);
            uint4 b0 = wp[0], b1 = wp[1];
            *(uint4*)&B_lds[lm * AROW + lko + 0] = b0;
            *(uint4*)&B_lds[lm * AROW + lko + 8] = b1;
        }
        __syncthreads();

        short8 af[4], bf[4];
#pragma unroll
        for (int mi = 0; mi < 4; mi++)
            af[mi] = *(const short8*)&A_lds[(wm * 64 + mi * 16 + l16) * AROW + q * 8];
#pragma unroll
        for (int ni = 0; ni < 4; ni++)
            bf[ni] = *(const short8*)&B_lds[(wn * 64 + ni * 16 + l16) * AROW + q * 8];
#pragma unroll
        for (int mi = 0; mi < 4; mi++)
#pragma unroll
            for (int ni = 0; ni < 4; ni++)
                acc[mi][ni] = __builtin_amdgcn_mfma_f32_16x16x32_bf16(af[mi], bf[ni], acc[mi][ni], 0, 0, 0);
    }

#pragma unroll
    for (int mi = 0; mi < 4; mi++) {
        int rbase = row0 + wm * 64 + mi * 16 + q * 4;
#pragma unroll
        for (int ni = 0; ni < 4; ni++) {
            int c = col0 + wn * 64 + ni * 16 + l16;
#pragma unroll
            for (int r = 0; r < 4; r++) {
                int gr = rbase + r;
                if (gr < NN) hbf[(size_t)gr * HD_ + c] = f2b(acc[mi][ni][r]);
            }
        }
    }

    int head = blockIdx.y * 2 + wn;
    float phs[4], phd[4];
#pragma unroll
    for (int ni = 0; ni < 4; ni++) {
        phs[ni] = phi[head * 128 + ni * 16 + l16];
        phd[ni] = phi[head * 128 + 64 + ni * 16 + l16];
    }
#pragma unroll
    for (int mi = 0; mi < 4; mi++) {
#pragma unroll
        for (int r = 0; r < 4; r++) {
            float ps = acc[mi][0][r] * phs[0] + acc[mi][1][r] * phs[1]
                     + acc[mi][2][r] * phs[2] + acc[mi][3][r] * phs[3];
            float pd = acc[mi][0][r] * phd[0] + acc[mi][1][r] * phd[1]
                     + acc[mi][2][r] * phd[2] + acc[mi][3][r] * phd[3];
#pragma unroll
            for (int o = 1; o < 16; o <<= 1) {
                ps += __shfl_xor(ps, o);
                pd += __shfl_xor(pd, o);
            }
            if (l16 == 0) {
                int gr = row0 + wm * 64 + mi * 16 + q * 4 + r;
                if (gr < NN) {
                    a_s[gr * 4 + head] = ps;
                    a_d[gr * 4 + head] = pd;
                }
            }
        }
    }
}

// ---------------- fill: direct-slot binning, 16B record {dst, w01, w23, 0} ----------------
__global__ void fill_edges(const int* __restrict__ src, const int* __restrict__ dstA,
                           int* __restrict__ cursor,
                           const float* __restrict__ a_s, const float* __restrict__ a_d,
                           uint4* __restrict__ edges) {
    int e = blockIdx.x * 256 + threadIdx.x;
    if (e >= EE) return;
    int s = src[e], d = dstA[e];
    int slot = atomicAdd(&cursor[s], 1);
    if (slot >= CAP_) return;   // statistically impossible; guarded
    float4 as4 = *(const float4*)(a_s + (size_t)s * 4);
    float4 ad4 = *(const float4*)(a_d + (size_t)d * 4);
    unsigned w01 = (unsigned)f2b(sigm(leaky(as4.x + ad4.x)))
                 | ((unsigned)f2b(sigm(leaky(as4.y + ad4.y))) << 16);
    unsigned w23 = (unsigned)f2b(sigm(leaky(as4.z + ad4.z)))
                 | ((unsigned)f2b(sigm(leaky(as4.w + ad4.w))) << 16);
    edges[(size_t)s * CAP_ + slot] = make_uint4((unsigned)d, w01, w23, 0u);
}

// ---------------- FUSED aggregation + MLP + softmax + preds ----------------
// 16 nodes/block (3125 blocks). 4 waves x 4 nodes gather -> LDS (bf16), then
// MFMA stage-1 (wave = one 16-hidden quarter, af from LDS = mlp's verified
// A-fragment pattern), z1 -> LDS, 16 threads do W2 + softmax + preds store.
// Kills the 25MB aggB write + 25MB read and one launch.
__global__ __launch_bounds__(256) void agg_mlp(const ushortT* __restrict__ hbf,
                                               const int* __restrict__ cursor,
                                               const uint4* __restrict__ edges,
                                               const ushortT* __restrict__ w1t,
                                               const float* __restrict__ b1,
                                               const float* __restrict__ W2,
                                               const float* __restrict__ b2,
                                               float* __restrict__ out) {
    __shared__ ushortT A_lds[16 * FROW];   // [local node][dim] bf16, padded
    __shared__ float z1t[16][68];          // [local node][hidden]
    const int tid = threadIdx.x;
    const int wave = tid >> 6, lane = tid & 63;
    const int q = lane >> 4, l16 = lane & 15;
    const int hsel = lane >> 4;
    const int wsh = (hsel & 1) * 16;
    const int n0 = blockIdx.x * 16;        // 3125 * 16 == 50000 exactly
    const ushortT* hbase = hbf + (size_t)lane * 4;

    // ---- phase 1: gather (wave handles 4 nodes) ----
#pragma unroll
    for (int ii = 0; ii < 4; ii++) {
        int ln = wave * 4 + ii;
        int n = n0 + ln;
        int cnt = cursor[n];
        if (cnt > CAP_) cnt = CAP_;
        int e0 = n * CAP_, e1 = e0 + cnt;
        float4 acc = make_float4(0.f, 0.f, 0.f, 0.f);

        int i = e0;
        while (i + 8 <= e1) {
            uint4 ee[8]; ushort4 hh[8]; float ww[8];
#pragma unroll
            for (int j = 0; j < 8; j++) ee[j] = edges[i + j];
#pragma unroll
            for (int j = 0; j < 8; j++) {
                unsigned pair = (hsel & 2) ? ee[j].z : ee[j].y;
                ww[j] = b2f((ushortT)((pair >> wsh) & 0xffffu));
                hh[j] = *(const ushort4*)(hbase + (size_t)ee[j].x * HD_);
            }
#pragma unroll
            for (int j = 0; j < 8; j++) {
                acc.x += b2f(hh[j].x) * ww[j];
                acc.y += b2f(hh[j].y) * ww[j];
                acc.z += b2f(hh[j].z) * ww[j];
                acc.w += b2f(hh[j].w) * ww[j];
            }
            i += 8;
        }
        while (i + 4 <= e1) {
            uint4 ee[4]; ushort4 hh[4]; float ww[4];
#pragma unroll
            for (int j = 0; j < 4; j++) ee[j] = edges[i + j];
#pragma unroll
            for (int j = 0; j < 4; j++) {
                unsigned pair = (hsel & 2) ? ee[j].z : ee[j].y;
                ww[j] = b2f((ushortT)((pair >> wsh) & 0xffffu));
                hh[j] = *(const ushort4*)(hbase + (size_t)ee[j].x * HD_);
            }
#pragma unroll
            for (int j = 0; j < 4; j++) {
                acc.x += b2f(hh[j].x) * ww[j];
                acc.y += b2f(hh[j].y) * ww[j];
                acc.z += b2f(hh[j].z) * ww[j];
                acc.w += b2f(hh[j].w) * ww[j];
            }
            i += 4;
        }
        for (; i < e1; i++) {
            uint4 e = edges[i];
            unsigned pair = (hsel & 2) ? e.z : e.y;
            float s = b2f((ushortT)((pair >> wsh) & 0xffffu));
            ushort4 hv = *(const ushort4*)(hbase + (size_t)e.x * HD_);
            acc.x += b2f(hv.x) * s; acc.y += b2f(hv.y) * s;
            acc.z += b2f(hv.z) * s; acc.w += b2f(hv.w) * s;
        }
        ushort4 o4 = make_ushort4(f2b(acc.x), f2b(acc.y), f2b(acc.z), f2b(acc.w));
        *(ushort4*)&A_lds[ln * FROW + lane * 4] = o4;
    }
    __syncthreads();

    // ---- phase 2: MFMA stage-1. wave = hidden quarter [16*wave, 16*wave+16) ----
    f32x4 macc = (f32x4){0.f, 0.f, 0.f, 0.f};
#pragma unroll
    for (int k0 = 0; k0 < 256; k0 += 32) {
        short8 af = *(const short8*)&A_lds[l16 * FROW + k0 + q * 8];
        short8 bf = *(const short8*)(w1t + (size_t)(wave * 16 + l16) * 256 + k0 + q * 8);
        macc = __builtin_amdgcn_mfma_f32_16x16x32_bf16(af, bf, macc, 0, 0, 0);
    }
    // C layout: col(hidden)=l16, row(node)=q*4+r
    {
        int o = wave * 16 + l16;
        float bb = b1[o];
#pragma unroll
        for (int r = 0; r < 4; r++)
            z1t[q * 4 + r][o] = leaky(macc[r] + bb);
    }
    __syncthreads();

    // ---- phase 3: z2 + softmax + preds (one thread per node) ----
    if (tid < 16) {
        int n = n0 + tid;
        float zc[NC_];
#pragma unroll
        for (int c = 0; c < NC_; c++) zc[c] = b2[c];
        for (int k = 0; k < 64; k += 4) {
            float4 z4 = *(const float4*)&z1t[tid][k];
#pragma unroll
            for (int j = 0; j < 4; j++) {
                float zv = (j == 0) ? z4.x : (j == 1) ? z4.y : (j == 2) ? z4.z : z4.w;
#pragma unroll
                for (int c = 0; c < NC_; c++) zc[c] += zv * W2[(k + j) * NC_ + c];
            }
        }
        float m = zc[0];
#pragma unroll
        for (int c = 1; c < NC_; c++) m = fmaxf(m, zc[c]);
        float ssum = 0.f;
#pragma unroll
        for (int c = 0; c < NC_; c++) { zc[c] = __expf(zc[c] - m) + EPS_; ssum += zc[c]; }
        float inv = 1.f / ssum;
#pragma unroll
        for (int c = 0; c < NC_; c++) out[1000 + (size_t)n * NC_ + c] = zc[c] * inv;
    }
}

// ---------------- group mean + log: one block per group ----------------
__global__ __launch_bounds__(256) void group_mean(const float* __restrict__ preds,
                                                  const int* __restrict__ gstart,
                                                  float* __restrict__ out) {
    __shared__ float red[16][16];
    int g = blockIdx.x;
    int t = threadIdx.x;
    int c = t & 15, chunk = t >> 4;
    int gs = gstart[g], ge = gstart[g + 1];
    float s = 0.f;
    if (c < NC_) {
        for (int n = gs + chunk; n < ge; n += 16) s += preds[(size_t)n * NC_ + c];
    }
    red[chunk][c] = s;
    __syncthreads();
    if (t < NC_) {
        float tot = 0.f;
#pragma unroll
        for (int j = 0; j < 16; j++) tot += red[j][t];
        out[g * NC_ + t] = __logf(tot / (float)(ge - gs));
    }
}

extern "C" void kernel_launch(void* const* d_in, const int* in_sizes, int n_in,
                              void* d_out, int out_size, void* d_ws, size_t ws_size,
                              hipStream_t stream) {
    const float* x      = (const float*)d_in[0];
    const int*   midx   = (const int*)d_in[1];
    const int*   batch  = (const int*)d_in[2];
    const float* W_feat = (const float*)d_in[3];
    const float* phi    = (const float*)d_in[4];
    const float* W1     = (const float*)d_in[5];
    const float* b1     = (const float*)d_in[6];
    const float* W2     = (const float*)d_in[7];
    const float* b2     = (const float*)d_in[8];
    const int* src = midx;
    const int* dst = midx + EE;
    float* out = (float*)d_out;

    char* p = (char*)d_ws;
    auto alloc = [&](size_t bytes) { void* r = (void*)p; p += (bytes + 255) & ~(size_t)255; return r; };
    ushortT* hbf      = (ushortT*)alloc((size_t)NN * HD_ * 2);
    uint4*   edges    = (uint4*)alloc((size_t)NN * CAP_ * 16);   // 38.4 MB
    ushortT* wt       = (ushortT*)alloc((size_t)DIN_ * HD_ * 2);
    ushortT* w1t      = (ushortT*)alloc((size_t)64 * 256 * 2);
    float*   a_s      = (float*)alloc((size_t)NN * 4 * 4);
    float*   a_d      = (float*)alloc((size_t)NN * 4 * 4);
    int*     cursor   = (int*)alloc((size_t)NN * 4);
    int*     gstart   = (int*)alloc((size_t)(NG_ + 1) * 4);

    setup_kernel<<<256, 256, 0, stream>>>(cursor, W_feat, wt, W1, w1t, batch, gstart);
    gemm_attn<<<dim3((NN + 127) / 128, 2), 256, 0, stream>>>(x, wt, phi, hbf, a_s, a_d);
    fill_edges<<<(EE + 255) / 256, 256, 0, stream>>>(src, dst, cursor, a_s, a_d, edges);
    agg_mlp<<<NN / 16, 256, 0, stream>>>(hbf, cursor, edges, w1t, b1, W2, b2, out);
    group_mean<<<NG_, 256, 0, stream>>>(out + 1000, gstart, out);
}